// Round 1
// baseline (723.619 us; speedup 1.0000x reference)
//
#include <hip/hip_runtime.h>

// EPCOR eval path on MI355X. Shapes fixed per reference setup.
#define BB 8
#define CC 64
#define NN 2048
#define MM 2048
#define KSEL 613            // 0-based index of the 614-th smallest (int(2048*0.3)=614)

// Output layout (floats): src_corr [B,3,N] | src_weight [B,N] | mask_src [B,N] | mask_tgt [B,M]
#define OUT_W  (BB * 3 * NN)          // 49152
#define OUT_MS (OUT_W + BB * NN)      // 65536
#define OUT_MT (OUT_MS + BB * NN)     // 81920

// ---------- K0: squared norms ----------
__global__ __launch_bounds__(256) void sqnorm_k(const float* __restrict__ E,
                                                float* __restrict__ out, int L) {
    int b = blockIdx.y;
    int i = blockIdx.x * 256 + threadIdx.x;
    const float* p = E + (size_t)b * CC * L + i;
    float s = 0.f;
#pragma unroll
    for (int c = 0; c < CC; ++c) { float v = p[(size_t)c * L]; s += v * v; }
    out[b * L + i] = s;
}

// ---------- K1: pd = 2*A^T B - xx - yy, stored [B,N,M] ----------
__global__ __launch_bounds__(256) void gemm_pd_k(const float* __restrict__ A,
                                                 const float* __restrict__ Bm,
                                                 const float* __restrict__ xx,
                                                 const float* __restrict__ yy,
                                                 float* __restrict__ pd) {
    __shared__ float As[CC][64];
    __shared__ float Bs[CC][64];
    int b = blockIdx.z;
    int n0 = blockIdx.y << 6;
    int m0 = blockIdx.x << 6;
    int t = threadIdx.x;
    const float4* Ag = (const float4*)(A + (size_t)b * CC * NN);
    const float4* Bg = (const float4*)(Bm + (size_t)b * CC * MM);
#pragma unroll
    for (int i = 0; i < 4; ++i) {
        int idx = t + (i << 8);      // 0..1023 float4 slots of the 64x64 tile
        int c = idx >> 4;
        int f4 = idx & 15;
        ((float4*)As)[idx] = Ag[c * (NN / 4) + (n0 >> 2) + f4];
        ((float4*)Bs)[idx] = Bg[c * (MM / 4) + (m0 >> 2) + f4];
    }
    __syncthreads();
    int tm = t & 15;    // m-group (consecutive threads -> consecutive m: coalesced stores)
    int tn = t >> 4;    // n-group
    float acc[4][4] = {{0.f}};
#pragma unroll 8
    for (int c = 0; c < CC; ++c) {
        float4 a4 = ((const float4*)As)[c * 16 + tn];
        float4 b4 = ((const float4*)Bs)[c * 16 + tm];
        float av[4] = {a4.x, a4.y, a4.z, a4.w};
        float bv[4] = {b4.x, b4.y, b4.z, b4.w};
#pragma unroll
        for (int i = 0; i < 4; ++i)
#pragma unroll
            for (int j = 0; j < 4; ++j) acc[i][j] += av[i] * bv[j];
    }
    float4 yv = *(const float4*)(yy + b * MM + m0 + (tm << 2));
#pragma unroll
    for (int i = 0; i < 4; ++i) {
        int n = n0 + (tn << 2) + i;
        float xv = xx[b * NN + n];
        float4 o;
        o.x = 2.f * acc[i][0] - xv - yv.x;
        o.y = 2.f * acc[i][1] - xv - yv.y;
        o.z = 2.f * acc[i][2] - xv - yv.z;
        o.w = 2.f * acc[i][3] - xv - yv.w;
        *(float4*)(pd + ((size_t)b * NN + n) * MM + m0 + (tm << 2)) = o;
    }
}

// ---------- K2: per-row max and sum(exp) ----------
__global__ __launch_bounds__(256) void row_stats_k(const float* __restrict__ pd,
                                                   float* __restrict__ rowmax,
                                                   float* __restrict__ rowsum) {
    int b = blockIdx.y, n = blockIdx.x, t = threadIdx.x;
    const float* row = pd + ((size_t)b * NN + n) * MM;
    float v[8];
    float mx = -3.4e38f;
#pragma unroll
    for (int i = 0; i < 8; ++i) { v[i] = row[t + (i << 8)]; mx = fmaxf(mx, v[i]); }
#pragma unroll
    for (int off = 32; off > 0; off >>= 1) mx = fmaxf(mx, __shfl_down(mx, off));
    __shared__ float wmax[4];
    __shared__ float wsum[4];
    int wave = t >> 6, lane = t & 63;
    if (lane == 0) wmax[wave] = mx;
    __syncthreads();
    mx = fmaxf(fmaxf(wmax[0], wmax[1]), fmaxf(wmax[2], wmax[3]));
    float sm = 0.f;
#pragma unroll
    for (int i = 0; i < 8; ++i) sm += expf(v[i] - mx);
#pragma unroll
    for (int off = 32; off > 0; off >>= 1) sm += __shfl_down(sm, off);
    if (lane == 0) wsum[wave] = sm;
    __syncthreads();
    if (t == 0) {
        rowmax[b * NN + n] = mx;
        rowsum[b * NN + n] = wsum[0] + wsum[1] + wsum[2] + wsum[3];
    }
}

// ---------- K3: per-column max and sum(exp); 64-column tiles ----------
__global__ __launch_bounds__(256) void col_stats_k(const float* __restrict__ pd,
                                                   float* __restrict__ colmax,
                                                   float* __restrict__ colsum) {
    int b = blockIdx.y;
    int m0 = blockIdx.x << 6;
    int t = threadIdx.x;
    int mL = t & 63, ng = t >> 6;
    const float* base = pd + (size_t)b * NN * MM + m0 + mL;
    float mx = -3.4e38f;
    for (int n = ng; n < NN; n += 4) mx = fmaxf(mx, base[(size_t)n * MM]);
    __shared__ float red[4][64];
    red[ng][mL] = mx;
    __syncthreads();
    mx = fmaxf(fmaxf(red[0][mL], red[1][mL]), fmaxf(red[2][mL], red[3][mL]));
    float sm = 0.f;
    for (int n = ng; n < NN; n += 4) sm += expf(base[(size_t)n * MM] - mx);
    __syncthreads();
    red[ng][mL] = sm;
    __syncthreads();
    if (ng == 0) {
        colmax[b * MM + m0 + mL] = mx;
        colsum[b * MM + m0 + mL] = red[0][mL] + red[1][mL] + red[2][mL] + red[3][mL];
    }
}

// ---------- K4: scoresRowSum[b,n] = sum_m exp(pd - colmax[m]) / colsum[m] ----------
__global__ __launch_bounds__(256) void srow_k(const float* __restrict__ pd,
                                              const float* __restrict__ colmax,
                                              const float* __restrict__ colsum,
                                              float* __restrict__ sRow) {
    int b = blockIdx.y, n = blockIdx.x, t = threadIdx.x;
    const float* row = pd + ((size_t)b * NN + n) * MM;
    float sm = 0.f;
#pragma unroll
    for (int i = 0; i < 8; ++i) {
        int m = t + (i << 8);
        sm += expf(row[m] - colmax[b * MM + m]) / colsum[b * MM + m];
    }
#pragma unroll
    for (int off = 32; off > 0; off >>= 1) sm += __shfl_down(sm, off);
    __shared__ float wsum[4];
    int wave = t >> 6, lane = t & 63;
    if (lane == 0) wsum[wave] = sm;
    __syncthreads();
    if (t == 0) sRow[b * NN + n] = wsum[0] + wsum[1] + wsum[2] + wsum[3];
}

// ---------- K5: scoresColSum[b,m] = sum_n exp(pd - rowmax[n]) / rowsum[n] ----------
__global__ __launch_bounds__(256) void scol_k(const float* __restrict__ pd,
                                              const float* __restrict__ rowmax,
                                              const float* __restrict__ rowsum,
                                              float* __restrict__ sCol) {
    int b = blockIdx.y;
    int m0 = blockIdx.x << 6;
    int t = threadIdx.x;
    int mL = t & 63, ng = t >> 6;
    const float* base = pd + (size_t)b * NN * MM + m0 + mL;
    float sm = 0.f;
    for (int n = ng; n < NN; n += 4)
        sm += expf(base[(size_t)n * MM] - rowmax[b * NN + n]) / rowsum[b * NN + n];
    __shared__ float red[4][64];
    red[ng][mL] = sm;
    __syncthreads();
    if (ng == 0)
        sCol[b * MM + m0 + mL] = red[0][mL] + red[1][mL] + red[2][mL] + red[3][mL];
}

// ---------- K6: 614-th smallest via binary search on float bits (values >= 0) ----------
__global__ __launch_bounds__(64) void select_k(const float* __restrict__ sRow,
                                               const float* __restrict__ sCol,
                                               float* __restrict__ rth,
                                               float* __restrict__ cth) {
    int kind = blockIdx.x, b = blockIdx.y, t = threadIdx.x;
    const float* vals = (kind == 0) ? (sRow + b * NN) : (sCol + b * MM);
    float v[32];
#pragma unroll
    for (int i = 0; i < 32; ++i) v[i] = vals[t + (i << 6)];
    unsigned lo = 0u, hi = 0x7F800000u;  // [+0, +inf]; values are finite non-negative
    while (lo < hi) {
        unsigned mid = lo + ((hi - lo) >> 1);
        float pv = __uint_as_float(mid);
        int c = 0;
#pragma unroll
        for (int i = 0; i < 32; ++i) c += (v[i] <= pv) ? 1 : 0;
#pragma unroll
        for (int off = 32; off > 0; off >>= 1) c += __shfl_down(c, off);
        c = __shfl(c, 0);
        if (c >= KSEL + 1) hi = mid; else lo = mid + 1;
    }
    if (t == 0) { if (kind == 0) rth[b] = __uint_as_float(lo); else cth[b] = __uint_as_float(lo); }
}

// ---------- K7: masks + src_weight ----------
__global__ __launch_bounds__(256) void masks_k(const float* __restrict__ sRow,
                                               const float* __restrict__ sCol,
                                               const float* __restrict__ rth,
                                               const float* __restrict__ cth,
                                               float* __restrict__ out) {
    int b = blockIdx.x, t = threadIdx.x;
    float r = rth[b], c = cth[b];
    int cnt = 0;
    bool ms[8];
#pragma unroll
    for (int i = 0; i < 8; ++i) {
        int n = t + (i << 8);
        ms[i] = sRow[b * NN + n] < r;
        out[OUT_MS + b * NN + n] = ms[i] ? 1.f : 0.f;
        out[OUT_MT + b * MM + n] = (sCol[b * MM + n] < c) ? 1.f : 0.f;
        cnt += ms[i] ? 0 : 1;
    }
#pragma unroll
    for (int off = 32; off > 0; off >>= 1) cnt += __shfl_down(cnt, off);
    __shared__ int wcnt[4];
    int wave = t >> 6, lane = t & 63;
    if (lane == 0) wcnt[wave] = cnt;
    __syncthreads();
    float inv = 1.f / (float)(wcnt[0] + wcnt[1] + wcnt[2] + wcnt[3]);
#pragma unroll
    for (int i = 0; i < 8; ++i) {
        int n = t + (i << 8);
        out[OUT_W + b * NN + n] = ms[i] ? 0.f : inv;
    }
}

// ---------- K8: src_corr = tgt @ w_sparse^T / colsum ----------
__global__ __launch_bounds__(256) void corr_k(const float* __restrict__ pd,
                                              const float* __restrict__ rowmax,
                                              const float* __restrict__ rowsum,
                                              const float* __restrict__ sRow,
                                              const float* __restrict__ sCol,
                                              const float* __restrict__ rth,
                                              const float* __restrict__ cth,
                                              const float* __restrict__ tgt,
                                              float* __restrict__ out) {
    int b = blockIdx.y, n = blockIdx.x, t = threadIdx.x;
    const float* row = pd + ((size_t)b * NN + n) * MM;
    const float* tg = tgt + (size_t)b * 3 * MM;
    float rmax = rowmax[b * NN + n];
    float rsum = rowsum[b * NN + n];
    float cthv = cth[b];
    bool msrc = sRow[b * NN + n] < rth[b];
    float cs = 0.f, d0 = 0.f, d1 = 0.f, d2 = 0.f;
#pragma unroll
    for (int i = 0; i < 8; ++i) {
        int m = t + (i << 8);
        float pdv = row[m];
        bool keep = msrc || (sCol[b * MM + m] < cthv) || (pdv == rmax);
        if (keep) {
            float s = expf(pdv - rmax) / rsum;
            cs += s;
            d0 += s * tg[m];
            d1 += s * tg[MM + m];
            d2 += s * tg[2 * MM + m];
        }
    }
#pragma unroll
    for (int off = 32; off > 0; off >>= 1) {
        cs += __shfl_down(cs, off);
        d0 += __shfl_down(d0, off);
        d1 += __shfl_down(d1, off);
        d2 += __shfl_down(d2, off);
    }
    __shared__ float red[4][4];
    int wave = t >> 6, lane = t & 63;
    if (lane == 0) { red[wave][0] = cs; red[wave][1] = d0; red[wave][2] = d1; red[wave][3] = d2; }
    __syncthreads();
    if (t == 0) {
        float cT = red[0][0] + red[1][0] + red[2][0] + red[3][0];
        float e0 = red[0][1] + red[1][1] + red[2][1] + red[3][1];
        float e1 = red[0][2] + red[1][2] + red[2][2] + red[3][2];
        float e2 = red[0][3] + red[1][3] + red[2][3] + red[3][3];
        cT = (cT < 1e-5f) ? 1e-5f : cT;
        out[(b * 3 + 0) * NN + n] = e0 / cT;
        out[(b * 3 + 1) * NN + n] = e1 / cT;
        out[(b * 3 + 2) * NN + n] = e2 / cT;
    }
}

extern "C" void kernel_launch(void* const* d_in, const int* in_sizes, int n_in,
                              void* d_out, int out_size, void* d_ws, size_t ws_size,
                              hipStream_t stream) {
    const float* src_emb = (const float*)d_in[0];   // [B,C,N]
    const float* tgt_emb = (const float*)d_in[1];   // [B,C,M]
    // d_in[2] = src, unused by the reference
    const float* tgt = (const float*)d_in[3];       // [B,3,M]
    float* out = (float*)d_out;

    float* ws = (float*)d_ws;
    float* pd     = ws;                               // B*N*M
    float* xx     = pd + (size_t)BB * NN * MM;        // B*N
    float* yy     = xx + BB * NN;                     // B*M
    float* rowmax = yy + BB * MM;                     // B*N
    float* rowsum = rowmax + BB * NN;                 // B*N
    float* colmax = rowsum + BB * NN;                 // B*M
    float* colsum = colmax + BB * MM;                 // B*M
    float* sRow   = colsum + BB * MM;                 // B*N
    float* sCol   = sRow + BB * NN;                   // B*M
    float* rth    = sCol + BB * MM;                   // B
    float* cth    = rth + BB;                         // B

    sqnorm_k<<<dim3(NN / 256, BB), 256, 0, stream>>>(src_emb, xx, NN);
    sqnorm_k<<<dim3(MM / 256, BB), 256, 0, stream>>>(tgt_emb, yy, MM);
    gemm_pd_k<<<dim3(MM / 64, NN / 64, BB), 256, 0, stream>>>(src_emb, tgt_emb, xx, yy, pd);
    row_stats_k<<<dim3(NN, BB), 256, 0, stream>>>(pd, rowmax, rowsum);
    col_stats_k<<<dim3(MM / 64, BB), 256, 0, stream>>>(pd, colmax, colsum);
    srow_k<<<dim3(NN, BB), 256, 0, stream>>>(pd, colmax, colsum, sRow);
    scol_k<<<dim3(MM / 64, BB), 256, 0, stream>>>(pd, rowmax, rowsum, sCol);
    select_k<<<dim3(2, BB), 64, 0, stream>>>(sRow, sCol, rth, cth);
    masks_k<<<dim3(BB), 256, 0, stream>>>(sRow, sCol, rth, cth, out);
    corr_k<<<dim3(NN, BB), 256, 0, stream>>>(pd, rowmax, rowsum, sRow, sCol, rth, cth, tgt, out);
}

// Round 2
// 289.971 us; speedup vs baseline: 2.4955x; 2.4955x over previous
//
#include <hip/hip_runtime.h>

// EPCOR eval path on MI355X. Shapes fixed per reference setup.
#define BB 8
#define CC 64
#define NN 2048
#define MM 2048
#define KSEL 613            // 0-based index of the 614-th smallest (int(2048*0.3)=614)
#define NCHUNK 16           // N split for column-reduction stage A (128 rows/chunk)

// Output layout (floats): src_corr [B,3,N] | src_weight [B,N] | mask_src [B,N] | mask_tgt [B,M]
#define OUT_W  (BB * 3 * NN)          // 49152
#define OUT_MS (OUT_W + BB * NN)      // 65536
#define OUT_MT (OUT_MS + BB * NN)     // 81920

// ---------- K0: squared norms ----------
__global__ __launch_bounds__(256) void sqnorm_k(const float* __restrict__ E,
                                                float* __restrict__ out, int L) {
    int b = blockIdx.y;
    int i = blockIdx.x * 256 + threadIdx.x;
    const float* p = E + (size_t)b * CC * L + i;
    float s = 0.f;
#pragma unroll
    for (int c = 0; c < CC; ++c) { float v = p[(size_t)c * L]; s += v * v; }
    out[b * L + i] = s;
}

// ---------- K1: pd = 2*A^T B - xx - yy, stored [B,N,M] ----------
__global__ __launch_bounds__(256) void gemm_pd_k(const float* __restrict__ A,
                                                 const float* __restrict__ Bm,
                                                 const float* __restrict__ xx,
                                                 const float* __restrict__ yy,
                                                 float* __restrict__ pd) {
    __shared__ float As[CC][64];
    __shared__ float Bs[CC][64];
    int b = blockIdx.z;
    int n0 = blockIdx.y << 6;
    int m0 = blockIdx.x << 6;
    int t = threadIdx.x;
    const float4* Ag = (const float4*)(A + (size_t)b * CC * NN);
    const float4* Bg = (const float4*)(Bm + (size_t)b * CC * MM);
#pragma unroll
    for (int i = 0; i < 4; ++i) {
        int idx = t + (i << 8);      // 0..1023 float4 slots of the 64x64 tile
        int c = idx >> 4;
        int f4 = idx & 15;
        ((float4*)As)[idx] = Ag[c * (NN / 4) + (n0 >> 2) + f4];
        ((float4*)Bs)[idx] = Bg[c * (MM / 4) + (m0 >> 2) + f4];
    }
    __syncthreads();
    int tm = t & 15;    // m-group (consecutive threads -> consecutive m: coalesced stores)
    int tn = t >> 4;    // n-group
    float acc[4][4] = {{0.f}};
#pragma unroll 8
    for (int c = 0; c < CC; ++c) {
        float4 a4 = ((const float4*)As)[c * 16 + tn];
        float4 b4 = ((const float4*)Bs)[c * 16 + tm];
        float av[4] = {a4.x, a4.y, a4.z, a4.w};
        float bv[4] = {b4.x, b4.y, b4.z, b4.w};
#pragma unroll
        for (int i = 0; i < 4; ++i)
#pragma unroll
            for (int j = 0; j < 4; ++j) acc[i][j] += av[i] * bv[j];
    }
    float4 yv = *(const float4*)(yy + b * MM + m0 + (tm << 2));
#pragma unroll
    for (int i = 0; i < 4; ++i) {
        int n = n0 + (tn << 2) + i;
        float xv = xx[b * NN + n];
        float4 o;
        o.x = 2.f * acc[i][0] - xv - yv.x;
        o.y = 2.f * acc[i][1] - xv - yv.y;
        o.z = 2.f * acc[i][2] - xv - yv.z;
        o.w = 2.f * acc[i][3] - xv - yv.w;
        *(float4*)(pd + ((size_t)b * NN + n) * MM + m0 + (tm << 2)) = o;
    }
}

// ---------- K2: per-row max and sum(exp), float4 loads ----------
__global__ __launch_bounds__(256) void row_stats_k(const float* __restrict__ pd,
                                                   float* __restrict__ rowmax,
                                                   float* __restrict__ rowsum) {
    int b = blockIdx.y, n = blockIdx.x, t = threadIdx.x;
    const float4* row4 = (const float4*)(pd + ((size_t)b * NN + n) * MM);
    float v[8];
    *(float4*)(v) = row4[t];
    *(float4*)(v + 4) = row4[t + 256];
    float mx = -3.4e38f;
#pragma unroll
    for (int i = 0; i < 8; ++i) mx = fmaxf(mx, v[i]);
#pragma unroll
    for (int off = 32; off > 0; off >>= 1) mx = fmaxf(mx, __shfl_down(mx, off));
    __shared__ float wmax[4];
    __shared__ float wsum[4];
    int wave = t >> 6, lane = t & 63;
    if (lane == 0) wmax[wave] = mx;
    __syncthreads();
    mx = fmaxf(fmaxf(wmax[0], wmax[1]), fmaxf(wmax[2], wmax[3]));
    float sm = 0.f;
#pragma unroll
    for (int i = 0; i < 8; ++i) sm += expf(v[i] - mx);
#pragma unroll
    for (int off = 32; off > 0; off >>= 1) sm += __shfl_down(sm, off);
    if (lane == 0) wsum[wave] = sm;
    __syncthreads();
    if (t == 0) {
        rowmax[b * NN + n] = mx;
        rowsum[b * NN + n] = wsum[0] + wsum[1] + wsum[2] + wsum[3];
    }
}

// ---------- K3a: column stats + scoresColSum partials; single pd read ----------
// Grid (M/64, NCHUNK, B). Each block: 64 cols x 128 rows, 32 rows/thread in regs.
__global__ __launch_bounds__(256) void colstatA_k(const float* __restrict__ pd,
                                                  const float* __restrict__ rowmax,
                                                  const float* __restrict__ rowsum,
                                                  float* __restrict__ cpmax,
                                                  float* __restrict__ cpsum,
                                                  float* __restrict__ scolp) {
    int b = blockIdx.z;
    int nc = blockIdx.y;
    int m0 = blockIdx.x << 6;
    int t = threadIdx.x, mL = t & 63, ng = t >> 6;
    __shared__ float rmx[128], rin[128];
    if (t < 128) {
        int n = nc * 128 + t;
        rmx[t] = rowmax[b * NN + n];
        rin[t] = 1.f / rowsum[b * NN + n];
    }
    __syncthreads();
    const float* base = pd + ((size_t)(b * NN + nc * 128)) * MM + m0 + mL;
    float v[32];
    float pmax = -3.4e38f;
#pragma unroll
    for (int i = 0; i < 32; ++i) {
        int n = (i << 2) + ng;                 // local row 0..127
        v[i] = base[(size_t)n * MM];
        pmax = fmaxf(pmax, v[i]);
    }
    float psum = 0.f, sc = 0.f;
#pragma unroll
    for (int i = 0; i < 32; ++i) {
        int n = (i << 2) + ng;
        psum += expf(v[i] - pmax);
        sc += expf(v[i] - rmx[n]) * rin[n];
    }
    __shared__ float rA[4][64], rB[4][64], rC[4][64];
    rA[ng][mL] = pmax; rB[ng][mL] = psum; rC[ng][mL] = sc;
    __syncthreads();
    if (ng == 0) {
        float Mv = fmaxf(fmaxf(rA[0][mL], rA[1][mL]), fmaxf(rA[2][mL], rA[3][mL]));
        float S = rB[0][mL] * expf(rA[0][mL] - Mv) + rB[1][mL] * expf(rA[1][mL] - Mv)
                + rB[2][mL] * expf(rA[2][mL] - Mv) + rB[3][mL] * expf(rA[3][mL] - Mv);
        float Cv = rC[0][mL] + rC[1][mL] + rC[2][mL] + rC[3][mL];
        size_t o = (size_t)(b * NCHUNK + nc) * MM + m0 + mL;
        cpmax[o] = Mv; cpsum[o] = S; scolp[o] = Cv;
    }
}

// ---------- K3b: combine column partials ----------
__global__ __launch_bounds__(256) void colcombine_k(const float* __restrict__ cpmax,
                                                    const float* __restrict__ cpsum,
                                                    const float* __restrict__ scolp,
                                                    float* __restrict__ colmax,
                                                    float* __restrict__ colsum,
                                                    float* __restrict__ sCol) {
    int b = blockIdx.y;
    int m = blockIdx.x * 256 + threadIdx.x;
    float Mv = -3.4e38f;
#pragma unroll
    for (int k = 0; k < NCHUNK; ++k)
        Mv = fmaxf(Mv, cpmax[(size_t)(b * NCHUNK + k) * MM + m]);
    float S = 0.f, Cv = 0.f;
#pragma unroll
    for (int k = 0; k < NCHUNK; ++k) {
        size_t o = (size_t)(b * NCHUNK + k) * MM + m;
        S += cpsum[o] * expf(cpmax[o] - Mv);
        Cv += scolp[o];
    }
    colmax[b * MM + m] = Mv;
    colsum[b * MM + m] = S;
    sCol[b * MM + m] = Cv;
}

// ---------- K4: scoresRowSum[b,n] = sum_m exp(pd - colmax[m]) / colsum[m], float4 ----------
__global__ __launch_bounds__(256) void srow_k(const float* __restrict__ pd,
                                              const float* __restrict__ colmax,
                                              const float* __restrict__ colsum,
                                              float* __restrict__ sRow) {
    int b = blockIdx.y, n = blockIdx.x, t = threadIdx.x;
    const float4* row4 = (const float4*)(pd + ((size_t)b * NN + n) * MM);
    const float4* cm4 = (const float4*)(colmax + b * MM);
    const float4* cs4 = (const float4*)(colsum + b * MM);
    float sm = 0.f;
#pragma unroll
    for (int g = 0; g < 2; ++g) {
        int j = t + (g << 8);
        float v[4], cm[4], cs[4];
        *(float4*)v = row4[j];
        *(float4*)cm = cm4[j];
        *(float4*)cs = cs4[j];
#pragma unroll
        for (int c = 0; c < 4; ++c) sm += expf(v[c] - cm[c]) / cs[c];
    }
#pragma unroll
    for (int off = 32; off > 0; off >>= 1) sm += __shfl_down(sm, off);
    __shared__ float wsum[4];
    int wave = t >> 6, lane = t & 63;
    if (lane == 0) wsum[wave] = sm;
    __syncthreads();
    if (t == 0) sRow[b * NN + n] = wsum[0] + wsum[1] + wsum[2] + wsum[3];
}

// ---------- K6: 614-th smallest via binary search on float bits (values >= 0) ----------
__global__ __launch_bounds__(64) void select_k(const float* __restrict__ sRow,
                                               const float* __restrict__ sCol,
                                               float* __restrict__ rth,
                                               float* __restrict__ cth) {
    int kind = blockIdx.x, b = blockIdx.y, t = threadIdx.x;
    const float* vals = (kind == 0) ? (sRow + b * NN) : (sCol + b * MM);
    float v[32];
#pragma unroll
    for (int i = 0; i < 32; ++i) v[i] = vals[t + (i << 6)];
    unsigned lo = 0u, hi = 0x7F800000u;  // [+0, +inf]; values are finite non-negative
    while (lo < hi) {
        unsigned mid = lo + ((hi - lo) >> 1);
        float pv = __uint_as_float(mid);
        int c = 0;
#pragma unroll
        for (int i = 0; i < 32; ++i) c += (v[i] <= pv) ? 1 : 0;
#pragma unroll
        for (int off = 32; off > 0; off >>= 1) c += __shfl_down(c, off);
        c = __shfl(c, 0);
        if (c >= KSEL + 1) hi = mid; else lo = mid + 1;
    }
    if (t == 0) { if (kind == 0) rth[b] = __uint_as_float(lo); else cth[b] = __uint_as_float(lo); }
}

// ---------- K7: masks + src_weight ----------
__global__ __launch_bounds__(256) void masks_k(const float* __restrict__ sRow,
                                               const float* __restrict__ sCol,
                                               const float* __restrict__ rth,
                                               const float* __restrict__ cth,
                                               float* __restrict__ out) {
    int b = blockIdx.x, t = threadIdx.x;
    float r = rth[b], c = cth[b];
    int cnt = 0;
    bool ms[8];
#pragma unroll
    for (int i = 0; i < 8; ++i) {
        int n = t + (i << 8);
        ms[i] = sRow[b * NN + n] < r;
        out[OUT_MS + b * NN + n] = ms[i] ? 1.f : 0.f;
        out[OUT_MT + b * MM + n] = (sCol[b * MM + n] < c) ? 1.f : 0.f;
        cnt += ms[i] ? 0 : 1;
    }
#pragma unroll
    for (int off = 32; off > 0; off >>= 1) cnt += __shfl_down(cnt, off);
    __shared__ int wcnt[4];
    int wave = t >> 6, lane = t & 63;
    if (lane == 0) wcnt[wave] = cnt;
    __syncthreads();
    float inv = 1.f / (float)(wcnt[0] + wcnt[1] + wcnt[2] + wcnt[3]);
#pragma unroll
    for (int i = 0; i < 8; ++i) {
        int n = t + (i << 8);
        out[OUT_W + b * NN + n] = ms[i] ? 0.f : inv;
    }
}

// ---------- K8: src_corr = tgt @ w_sparse^T / colsum, float4 ----------
__global__ __launch_bounds__(256) void corr_k(const float* __restrict__ pd,
                                              const float* __restrict__ rowmax,
                                              const float* __restrict__ rowsum,
                                              const float* __restrict__ sRow,
                                              const float* __restrict__ sCol,
                                              const float* __restrict__ rth,
                                              const float* __restrict__ cth,
                                              const float* __restrict__ tgt,
                                              float* __restrict__ out) {
    int b = blockIdx.y, n = blockIdx.x, t = threadIdx.x;
    const float4* row4 = (const float4*)(pd + ((size_t)b * NN + n) * MM);
    const float4* sc4 = (const float4*)(sCol + b * MM);
    const float4* tg4 = (const float4*)(tgt + (size_t)b * 3 * MM);
    float rmax = rowmax[b * NN + n];
    float rsum = rowsum[b * NN + n];
    float cthv = cth[b];
    bool msrc = sRow[b * NN + n] < rth[b];
    float cs = 0.f, d0 = 0.f, d1 = 0.f, d2 = 0.f;
#pragma unroll
    for (int g = 0; g < 2; ++g) {
        int j = t + (g << 8);
        float p[4], sc[4], t0[4], t1[4], t2[4];
        *(float4*)p = row4[j];
        *(float4*)sc = sc4[j];
        *(float4*)t0 = tg4[j];
        *(float4*)t1 = tg4[j + MM / 4];
        *(float4*)t2 = tg4[j + MM / 2];
#pragma unroll
        for (int c = 0; c < 4; ++c) {
            bool keep = msrc || (sc[c] < cthv) || (p[c] == rmax);
            if (keep) {
                float s = expf(p[c] - rmax) / rsum;
                cs += s;
                d0 += s * t0[c];
                d1 += s * t1[c];
                d2 += s * t2[c];
            }
        }
    }
#pragma unroll
    for (int off = 32; off > 0; off >>= 1) {
        cs += __shfl_down(cs, off);
        d0 += __shfl_down(d0, off);
        d1 += __shfl_down(d1, off);
        d2 += __shfl_down(d2, off);
    }
    __shared__ float red[4][4];
    int wave = t >> 6, lane = t & 63;
    if (lane == 0) { red[wave][0] = cs; red[wave][1] = d0; red[wave][2] = d1; red[wave][3] = d2; }
    __syncthreads();
    if (t == 0) {
        float cT = red[0][0] + red[1][0] + red[2][0] + red[3][0];
        float e0 = red[0][1] + red[1][1] + red[2][1] + red[3][1];
        float e1 = red[0][2] + red[1][2] + red[2][2] + red[3][2];
        float e2 = red[0][3] + red[1][3] + red[2][3] + red[3][3];
        cT = (cT < 1e-5f) ? 1e-5f : cT;
        out[(b * 3 + 0) * NN + n] = e0 / cT;
        out[(b * 3 + 1) * NN + n] = e1 / cT;
        out[(b * 3 + 2) * NN + n] = e2 / cT;
    }
}

extern "C" void kernel_launch(void* const* d_in, const int* in_sizes, int n_in,
                              void* d_out, int out_size, void* d_ws, size_t ws_size,
                              hipStream_t stream) {
    const float* src_emb = (const float*)d_in[0];   // [B,C,N]
    const float* tgt_emb = (const float*)d_in[1];   // [B,C,M]
    // d_in[2] = src, unused by the reference
    const float* tgt = (const float*)d_in[3];       // [B,3,M]
    float* out = (float*)d_out;

    float* ws = (float*)d_ws;
    float* pd     = ws;                               // B*N*M
    float* xx     = pd + (size_t)BB * NN * MM;        // B*N
    float* yy     = xx + BB * NN;                     // B*M
    float* rowmax = yy + BB * MM;                     // B*N
    float* rowsum = rowmax + BB * NN;                 // B*N
    float* colmax = rowsum + BB * NN;                 // B*M
    float* colsum = colmax + BB * MM;                 // B*M
    float* sRow   = colsum + BB * MM;                 // B*N
    float* sCol   = sRow + BB * NN;                   // B*M
    float* rth    = sCol + BB * MM;                   // B
    float* cth    = rth + BB;                         // B
    float* cpmax  = cth + BB;                         // B*NCHUNK*M
    float* cpsum  = cpmax + (size_t)BB * NCHUNK * MM; // B*NCHUNK*M
    float* scolp  = cpsum + (size_t)BB * NCHUNK * MM; // B*NCHUNK*M

    sqnorm_k<<<dim3(NN / 256, BB), 256, 0, stream>>>(src_emb, xx, NN);
    sqnorm_k<<<dim3(MM / 256, BB), 256, 0, stream>>>(tgt_emb, yy, MM);
    gemm_pd_k<<<dim3(MM / 64, NN / 64, BB), 256, 0, stream>>>(src_emb, tgt_emb, xx, yy, pd);
    row_stats_k<<<dim3(NN, BB), 256, 0, stream>>>(pd, rowmax, rowsum);
    colstatA_k<<<dim3(MM / 64, NCHUNK, BB), 256, 0, stream>>>(pd, rowmax, rowsum, cpmax, cpsum, scolp);
    colcombine_k<<<dim3(MM / 256, BB), 256, 0, stream>>>(cpmax, cpsum, scolp, colmax, colsum, sCol);
    srow_k<<<dim3(NN, BB), 256, 0, stream>>>(pd, colmax, colsum, sRow);
    select_k<<<dim3(2, BB), 64, 0, stream>>>(sRow, sCol, rth, cth);
    masks_k<<<dim3(BB), 256, 0, stream>>>(sRow, sCol, rth, cth, out);
    corr_k<<<dim3(NN, BB), 256, 0, stream>>>(pd, rowmax, rowsum, sRow, sCol, rth, cth, tgt, out);
}

// Round 3
// 264.713 us; speedup vs baseline: 2.7336x; 1.0954x over previous
//
#include <hip/hip_runtime.h>

// EPCOR eval path on MI355X. Shapes fixed per reference setup.
#define BB 8
#define CC 64
#define NN 2048
#define MM 2048
#define KSEL 613            // 0-based index of the 614-th smallest (int(2048*0.3)=614)
#define MT 32               // m tiles of 64 (gemm + cross)
#define NT 32               // n tiles of 64 (gemm)
#define NCH 16              // n chunks of 128 (cross pass)

// Output layout (floats): src_corr [B,3,N] | src_weight [B,N] | mask_src [B,N] | mask_tgt [B,M]
#define OUT_W  (BB * 3 * NN)          // 49152
#define OUT_MS (OUT_W + BB * NN)      // 65536
#define OUT_MT (OUT_MS + BB * NN)     // 81920

// ---------- K0: squared norms ----------
__global__ __launch_bounds__(256) void sqnorm_k(const float* __restrict__ E,
                                                float* __restrict__ out, int L) {
    int b = blockIdx.y;
    int i = blockIdx.x * 256 + threadIdx.x;
    const float* p = E + (size_t)b * CC * L + i;
    float s = 0.f;
#pragma unroll
    for (int c = 0; c < CC; ++c) { float v = p[(size_t)c * L]; s += v * v; }
    out[b * L + i] = s;
}

// ---------- K1: pd = 2*A^T B - xx - yy, stored [B,N,M]; fused row/col softmax-stat partials ----------
__global__ __launch_bounds__(256) void gemm_pd_k(const float* __restrict__ A,
                                                 const float* __restrict__ Bm,
                                                 const float* __restrict__ xx,
                                                 const float* __restrict__ yy,
                                                 float* __restrict__ pd,
                                                 float* __restrict__ rpM,  // [B,MT,N]
                                                 float* __restrict__ rpS,  // [B,MT,N]
                                                 float* __restrict__ cpM,  // [B,NT,M]
                                                 float* __restrict__ cpS) {// [B,NT,M]
    __shared__ float As[CC][64];
    __shared__ float Bs[CC][64];
    __shared__ float cred[64][17];   // padded: conflict-light
    __shared__ float cmaxs[64];
    int b = blockIdx.z;
    int n0 = blockIdx.y << 6;
    int m0 = blockIdx.x << 6;
    int t = threadIdx.x;
    const float4* Ag = (const float4*)(A + (size_t)b * CC * NN);
    const float4* Bg = (const float4*)(Bm + (size_t)b * CC * MM);
#pragma unroll
    for (int i = 0; i < 4; ++i) {
        int idx = t + (i << 8);
        int c = idx >> 4;
        int f4 = idx & 15;
        ((float4*)As)[idx] = Ag[c * (NN / 4) + (n0 >> 2) + f4];
        ((float4*)Bs)[idx] = Bg[c * (MM / 4) + (m0 >> 2) + f4];
    }
    __syncthreads();
    int tm = t & 15;    // m-group
    int tn = t >> 4;    // n-group
    float acc[4][4] = {{0.f}};
#pragma unroll 8
    for (int c = 0; c < CC; ++c) {
        float4 a4 = ((const float4*)As)[c * 16 + tn];
        float4 b4 = ((const float4*)Bs)[c * 16 + tm];
        float av[4] = {a4.x, a4.y, a4.z, a4.w};
        float bv[4] = {b4.x, b4.y, b4.z, b4.w};
#pragma unroll
        for (int i = 0; i < 4; ++i)
#pragma unroll
            for (int j = 0; j < 4; ++j) acc[i][j] += av[i] * bv[j];
    }
    float4 yv = *(const float4*)(yy + b * MM + m0 + (tm << 2));
    float yvv[4] = {yv.x, yv.y, yv.z, yv.w};
    float o[4][4];
#pragma unroll
    for (int i = 0; i < 4; ++i) {
        int n = n0 + (tn << 2) + i;
        float xv = xx[b * NN + n];
#pragma unroll
        for (int j = 0; j < 4; ++j) o[i][j] = 2.f * acc[i][j] - xv - yvv[j];
        *(float4*)(pd + ((size_t)b * NN + n) * MM + m0 + (tm << 2)) =
            make_float4(o[i][0], o[i][1], o[i][2], o[i][3]);
    }
    // --- row partials: reduce across the 16 tm-lanes (consecutive within a wave) ---
    float rm4[4], rs4[4];
#pragma unroll
    for (int i = 0; i < 4; ++i) {
        float rm = fmaxf(fmaxf(o[i][0], o[i][1]), fmaxf(o[i][2], o[i][3]));
#pragma unroll
        for (int d = 1; d < 16; d <<= 1) rm = fmaxf(rm, __shfl_xor(rm, d));
        float rs = expf(o[i][0] - rm) + expf(o[i][1] - rm) + expf(o[i][2] - rm) + expf(o[i][3] - rm);
#pragma unroll
        for (int d = 1; d < 16; d <<= 1) rs += __shfl_xor(rs, d);
        rm4[i] = rm; rs4[i] = rs;
    }
    if (tm == 0) {
        size_t base = ((size_t)(b * MT + blockIdx.x)) * NN + n0 + (tn << 2);
        *(float4*)&rpM[base] = make_float4(rm4[0], rm4[1], rm4[2], rm4[3]);
        *(float4*)&rpS[base] = make_float4(rs4[0], rs4[1], rs4[2], rs4[3]);
    }
    // --- col partials: LDS reduce across the 16 tn-groups ---
#pragma unroll
    for (int j = 0; j < 4; ++j) {
        float cm = fmaxf(fmaxf(o[0][j], o[1][j]), fmaxf(o[2][j], o[3][j]));
        cred[(tm << 2) + j][tn] = cm;
    }
    __syncthreads();
    if (t < 64) {
        float cm = cred[t][0];
#pragma unroll
        for (int r = 1; r < 16; ++r) cm = fmaxf(cm, cred[t][r]);
        cmaxs[t] = cm;
    }
    __syncthreads();
#pragma unroll
    for (int j = 0; j < 4; ++j) {
        float m_ = cmaxs[(tm << 2) + j];
        float cs = expf(o[0][j] - m_) + expf(o[1][j] - m_) + expf(o[2][j] - m_) + expf(o[3][j] - m_);
        cred[(tm << 2) + j][tn] = cs;
    }
    __syncthreads();
    if (t < 64) {
        float cs = cred[t][0];
#pragma unroll
        for (int r = 1; r < 16; ++r) cs += cred[t][r];
        size_t base = ((size_t)(b * NT + blockIdx.y)) * MM + m0 + t;
        cpM[base] = cmaxs[t];
        cpS[base] = cs;
    }
}

// ---------- K2: combine row/col partials (online softmax merge). z=0 rows, z=1 cols ----------
__global__ __launch_bounds__(256) void comb_rc_k(const float* __restrict__ rpM,
                                                 const float* __restrict__ rpS,
                                                 const float* __restrict__ cpM,
                                                 const float* __restrict__ cpS,
                                                 float* __restrict__ rowmax,
                                                 float* __restrict__ rowsum,
                                                 float* __restrict__ colmax,
                                                 float* __restrict__ colsum) {
    int b = blockIdx.y, which = blockIdx.z;
    int i = blockIdx.x * 256 + threadIdx.x;
    const float* pM = which ? cpM : rpM;
    const float* pS = which ? cpS : rpS;
    float* oM = which ? colmax : rowmax;
    float* oS = which ? colsum : rowsum;
    float Mv = -3.4e38f;
#pragma unroll
    for (int k = 0; k < 32; ++k) Mv = fmaxf(Mv, pM[(size_t)(b * 32 + k) * 2048 + i]);
    float S = 0.f;
#pragma unroll
    for (int k = 0; k < 32; ++k) {
        size_t o = (size_t)(b * 32 + k) * 2048 + i;
        S += pS[o] * expf(pM[o] - Mv);
    }
    oM[b * 2048 + i] = Mv;
    oS[b * 2048 + i] = S;
}

// ---------- K3: fused cross pass — sRow partials AND sCol partials, single pd read ----------
// Grid (MT, NCH, B). Block: 64 cols x 128 rows; thread (mL,ng) walks 32 rows of one column.
__global__ __launch_bounds__(256) void cross_k(const float* __restrict__ pd,
                                               const float* __restrict__ rowmax,
                                               const float* __restrict__ rowsum,
                                               const float* __restrict__ colmax,
                                               const float* __restrict__ colsum,
                                               float* __restrict__ sRowp,   // [B,MT,N]
                                               float* __restrict__ sColp) { // [B,NCH,M]
    __shared__ float rmx[128], rin[128];
    __shared__ float rowpart[128][65];  // pad 65: conflict-free scalar access
    __shared__ float colacc[4][64];
    int b = blockIdx.z, nc = blockIdx.y, mtile = blockIdx.x;
    int m0 = mtile << 6;
    int t = threadIdx.x, mL = t & 63, ng = t >> 6;
    if (t < 128) {
        int n = nc * 128 + t;
        rmx[t] = rowmax[b * NN + n];
        rin[t] = 1.f / rowsum[b * NN + n];
    }
    float cmv = colmax[b * MM + m0 + mL];
    float civ = 1.f / colsum[b * MM + m0 + mL];
    __syncthreads();
    const float* base = pd + ((size_t)(b * NN + nc * 128)) * MM + m0 + mL;
    float scp = 0.f;
#pragma unroll
    for (int i = 0; i < 32; ++i) {
        int nl = (i << 2) + ng;
        float v = base[(size_t)nl * MM];
        scp += expf(v - rmx[nl]) * rin[nl];
        rowpart[nl][mL] = expf(v - cmv) * civ;
    }
    colacc[ng][mL] = scp;
    __syncthreads();
    if (t < 128) {
        float s = 0.f;
#pragma unroll
        for (int c = 0; c < 64; ++c) s += rowpart[t][c];
        sRowp[((size_t)(b * MT + mtile)) * NN + nc * 128 + t] = s;
    } else if (t < 192) {
        int m = t - 128;
        sColp[((size_t)(b * NCH + nc)) * MM + m0 + m] =
            colacc[0][m] + colacc[1][m] + colacc[2][m] + colacc[3][m];
    }
}

// ---------- K4: combine cross partials. z=0: sRow (32 tiles), z=1: sCol (16 chunks) ----------
__global__ __launch_bounds__(256) void comb_s_k(const float* __restrict__ sRowp,
                                                const float* __restrict__ sColp,
                                                float* __restrict__ sRow,
                                                float* __restrict__ sCol) {
    int b = blockIdx.y, which = blockIdx.z;
    int i = blockIdx.x * 256 + threadIdx.x;
    if (!which) {
        float s = 0.f;
#pragma unroll
        for (int k = 0; k < MT; ++k) s += sRowp[(size_t)(b * MT + k) * NN + i];
        sRow[b * NN + i] = s;
    } else {
        float s = 0.f;
#pragma unroll
        for (int k = 0; k < NCH; ++k) s += sColp[(size_t)(b * NCH + k) * MM + i];
        sCol[b * MM + i] = s;
    }
}

// ---------- K5: 614-th smallest via binary search on float bits (values >= 0) ----------
__global__ __launch_bounds__(64) void select_k(const float* __restrict__ sRow,
                                               const float* __restrict__ sCol,
                                               float* __restrict__ rth,
                                               float* __restrict__ cth) {
    int kind = blockIdx.x, b = blockIdx.y, t = threadIdx.x;
    const float* vals = (kind == 0) ? (sRow + b * NN) : (sCol + b * MM);
    float v[32];
#pragma unroll
    for (int i = 0; i < 32; ++i) v[i] = vals[t + (i << 6)];
    unsigned lo = 0u, hi = 0x7F800000u;
    while (lo < hi) {
        unsigned mid = lo + ((hi - lo) >> 1);
        float pv = __uint_as_float(mid);
        int c = 0;
#pragma unroll
        for (int i = 0; i < 32; ++i) c += (v[i] <= pv) ? 1 : 0;
#pragma unroll
        for (int off = 32; off > 0; off >>= 1) c += __shfl_down(c, off);
        c = __shfl(c, 0);
        if (c >= KSEL + 1) hi = mid; else lo = mid + 1;
    }
    if (t == 0) { if (kind == 0) rth[b] = __uint_as_float(lo); else cth[b] = __uint_as_float(lo); }
}

// ---------- K6: masks + src_weight ----------
__global__ __launch_bounds__(256) void masks_k(const float* __restrict__ sRow,
                                               const float* __restrict__ sCol,
                                               const float* __restrict__ rth,
                                               const float* __restrict__ cth,
                                               float* __restrict__ out) {
    int b = blockIdx.x, t = threadIdx.x;
    float r = rth[b], c = cth[b];
    int cnt = 0;
    bool ms[8];
#pragma unroll
    for (int i = 0; i < 8; ++i) {
        int n = t + (i << 8);
        ms[i] = sRow[b * NN + n] < r;
        out[OUT_MS + b * NN + n] = ms[i] ? 1.f : 0.f;
        out[OUT_MT + b * MM + n] = (sCol[b * MM + n] < c) ? 1.f : 0.f;
        cnt += ms[i] ? 0 : 1;
    }
#pragma unroll
    for (int off = 32; off > 0; off >>= 1) cnt += __shfl_down(cnt, off);
    __shared__ int wcnt[4];
    int wave = t >> 6, lane = t & 63;
    if (lane == 0) wcnt[wave] = cnt;
    __syncthreads();
    float inv = 1.f / (float)(wcnt[0] + wcnt[1] + wcnt[2] + wcnt[3]);
#pragma unroll
    for (int i = 0; i < 8; ++i) {
        int n = t + (i << 8);
        out[OUT_W + b * NN + n] = ms[i] ? 0.f : inv;
    }
}

// ---------- K7: src_corr = tgt @ w_sparse^T / colsum, float4 ----------
__global__ __launch_bounds__(256) void corr_k(const float* __restrict__ pd,
                                              const float* __restrict__ rowmax,
                                              const float* __restrict__ rowsum,
                                              const float* __restrict__ sRow,
                                              const float* __restrict__ sCol,
                                              const float* __restrict__ rth,
                                              const float* __restrict__ cth,
                                              const float* __restrict__ tgt,
                                              float* __restrict__ out) {
    int b = blockIdx.y, n = blockIdx.x, t = threadIdx.x;
    const float4* row4 = (const float4*)(pd + ((size_t)b * NN + n) * MM);
    const float4* sc4 = (const float4*)(sCol + b * MM);
    const float4* tg4 = (const float4*)(tgt + (size_t)b * 3 * MM);
    float rmax = rowmax[b * NN + n];
    float rsum = rowsum[b * NN + n];
    float cthv = cth[b];
    bool msrc = sRow[b * NN + n] < rth[b];
    float cs = 0.f, d0 = 0.f, d1 = 0.f, d2 = 0.f;
#pragma unroll
    for (int g = 0; g < 2; ++g) {
        int j = t + (g << 8);
        float p[4], sc[4], t0[4], t1[4], t2[4];
        *(float4*)p = row4[j];
        *(float4*)sc = sc4[j];
        *(float4*)t0 = tg4[j];
        *(float4*)t1 = tg4[j + MM / 4];
        *(float4*)t2 = tg4[j + MM / 2];
#pragma unroll
        for (int c = 0; c < 4; ++c) {
            bool keep = msrc || (sc[c] < cthv) || (p[c] == rmax);
            if (keep) {
                float s = expf(p[c] - rmax) / rsum;
                cs += s;
                d0 += s * t0[c];
                d1 += s * t1[c];
                d2 += s * t2[c];
            }
        }
    }
#pragma unroll
    for (int off = 32; off > 0; off >>= 1) {
        cs += __shfl_down(cs, off);
        d0 += __shfl_down(d0, off);
        d1 += __shfl_down(d1, off);
        d2 += __shfl_down(d2, off);
    }
    __shared__ float red[4][4];
    int wave = t >> 6, lane = t & 63;
    if (lane == 0) { red[wave][0] = cs; red[wave][1] = d0; red[wave][2] = d1; red[wave][3] = d2; }
    __syncthreads();
    if (t == 0) {
        float cT = red[0][0] + red[1][0] + red[2][0] + red[3][0];
        float e0 = red[0][1] + red[1][1] + red[2][1] + red[3][1];
        float e1 = red[0][2] + red[1][2] + red[2][2] + red[3][2];
        float e2 = red[0][3] + red[1][3] + red[2][3] + red[3][3];
        cT = (cT < 1e-5f) ? 1e-5f : cT;
        out[(b * 3 + 0) * NN + n] = e0 / cT;
        out[(b * 3 + 1) * NN + n] = e1 / cT;
        out[(b * 3 + 2) * NN + n] = e2 / cT;
    }
}

extern "C" void kernel_launch(void* const* d_in, const int* in_sizes, int n_in,
                              void* d_out, int out_size, void* d_ws, size_t ws_size,
                              hipStream_t stream) {
    const float* src_emb = (const float*)d_in[0];   // [B,C,N]
    const float* tgt_emb = (const float*)d_in[1];   // [B,C,M]
    // d_in[2] = src, unused by the reference
    const float* tgt = (const float*)d_in[3];       // [B,3,M]
    float* out = (float*)d_out;

    float* ws = (float*)d_ws;
    float* pd     = ws;                               // B*N*M
    float* xx     = pd + (size_t)BB * NN * MM;        // B*N
    float* yy     = xx + BB * NN;                     // B*M
    float* rowmax = yy + BB * MM;                     // B*N
    float* rowsum = rowmax + BB * NN;                 // B*N
    float* colmax = rowsum + BB * NN;                 // B*M
    float* colsum = colmax + BB * MM;                 // B*M
    float* sRow   = colsum + BB * MM;                 // B*N
    float* sCol   = sRow + BB * NN;                   // B*M
    float* rth    = sCol + BB * MM;                   // B
    float* cth    = rth + BB;                         // B
    float* rpM    = cth + BB;                         // B*MT*N
    float* rpS    = rpM + (size_t)BB * MT * NN;       // B*MT*N
    float* cpM    = rpS + (size_t)BB * MT * NN;       // B*NT*M
    float* cpS    = cpM + (size_t)BB * NT * MM;       // B*NT*M
    float* sRowp  = cpS + (size_t)BB * NT * MM;       // B*MT*N
    float* sColp  = sRowp + (size_t)BB * MT * NN;     // B*NCH*M

    sqnorm_k<<<dim3(NN / 256, BB), 256, 0, stream>>>(src_emb, xx, NN);
    sqnorm_k<<<dim3(MM / 256, BB), 256, 0, stream>>>(tgt_emb, yy, MM);
    gemm_pd_k<<<dim3(MM / 64, NN / 64, BB), 256, 0, stream>>>(src_emb, tgt_emb, xx, yy, pd,
                                                              rpM, rpS, cpM, cpS);
    comb_rc_k<<<dim3(2048 / 256, BB, 2), 256, 0, stream>>>(rpM, rpS, cpM, cpS,
                                                           rowmax, rowsum, colmax, colsum);
    cross_k<<<dim3(MT, NCH, BB), 256, 0, stream>>>(pd, rowmax, rowsum, colmax, colsum, sRowp, sColp);
    comb_s_k<<<dim3(2048 / 256, BB, 2), 256, 0, stream>>>(sRowp, sColp, sRow, sCol);
    select_k<<<dim3(2, BB), 64, 0, stream>>>(sRow, sCol, rth, cth);
    masks_k<<<dim3(BB), 256, 0, stream>>>(sRow, sCol, rth, cth, out);
    corr_k<<<dim3(NN, BB), 256, 0, stream>>>(pd, rowmax, rowsum, sRow, sCol, rth, cth, tgt, out);
}